// Round 5
// baseline (320.215 us; speedup 1.0000x reference)
//
#include <hip/hip_runtime.h>
#include <stdint.h>

#define TT 2048
#define HH 16
#define LOG2E 1.44269504089f

typedef _Float16 f16;
typedef __attribute__((ext_vector_type(8))) _Float16 f16x8;
typedef __attribute__((ext_vector_type(2))) __fp16 fp16x2;   // matches cvt_pkrtz return type
typedef __attribute__((ext_vector_type(4))) float f32x4;
typedef unsigned short ushort_t;

// async global->LDS, 16B per lane
__device__ __forceinline__ void gl_lds16(const void* g, void* l){
  __builtin_amdgcn_global_load_lds(
      (__attribute__((address_space(1))) void*)(void*)g,
      (__attribute__((address_space(3))) void*)l, 16, 0, 0);
}

// barrier WITHOUT vmcnt drain: LDS ops done, but global loads stay in flight
__device__ __forceinline__ void lds_barrier(){
  __asm__ volatile("s_waitcnt lgkmcnt(0)\n\ts_barrier" ::: "memory");
}

// ---------------- transpose+convert: f32 [R][C] -> f16 [C][R] ----------------
__global__ __launch_bounds__(256) void transpose_cvt_kernel(const float* __restrict__ in,
                                                            f16* __restrict__ out, int R, int C){
  __shared__ float tile[64][65];
  int c0 = blockIdx.x * 64, r0 = blockIdx.y * 64;
  int t = threadIdx.x;
  int row = t >> 2, cs = (t & 3) << 4;
  const float4* src = (const float4*)(in + (size_t)(r0 + row) * C + c0 + cs);
  float4 a = src[0], b = src[1], c = src[2], d = src[3];
  float* tr = &tile[row][cs];
  tr[0]=a.x; tr[1]=a.y; tr[2]=a.z;  tr[3]=a.w;
  tr[4]=b.x; tr[5]=b.y; tr[6]=b.z;  tr[7]=b.w;
  tr[8]=c.x; tr[9]=c.y; tr[10]=c.z; tr[11]=c.w;
  tr[12]=d.x;tr[13]=d.y;tr[14]=d.z; tr[15]=d.w;
  __syncthreads();
  f16 tmp[16];
  #pragma unroll
  for (int j = 0; j < 16; ++j) tmp[j] = (f16)tile[cs + j][row];
  f16* dst = out + (size_t)(c0 + row) * R + r0 + cs;
  *(uint4*)dst = *(uint4*)&tmp[0];
  *(uint4*)(dst + 8) = *(uint4*)&tmp[8];
}

// ---------------- GEMM with fused f32->f16 A conversion ----------------
// C[M][N] = cvt(A_f32)[M][K] @ Bt[N][K]^T, f16 out. As pitch 40 (80B, 16B-aligned).
__global__ __launch_bounds__(256) void gemm_xa_kernel(const float* __restrict__ A,
                                                      const f16* __restrict__ Bt,
                                                      f16* __restrict__ Cout,
                                                      int M, int N, int K){
  __shared__ __align__(16) f16 As[128 * 40];
  __shared__ __align__(16) f16 Bs[128 * 32];
  int t = threadIdx.x;
  int w = t >> 6, lane = t & 63;
  int wm = (w >> 1) * 64, wn = (w & 1) * 64;
  int lrow = lane & 15, quad = lane >> 4;
  int bm = blockIdx.y, bn = blockIdx.x;

  int arow = t >> 1, acol = (t & 1) << 4;
  const float* abase = A + (size_t)((bm << 7) + arow) * K + acol;

  f32x4 acc[4][4];
  for (int i = 0; i < 4; ++i)
    for (int j = 0; j < 4; ++j)
      for (int r = 0; r < 4; ++r) acc[i][j][r] = 0.f;

  const int nk = K >> 5;
  for (int kt = 0; kt < nk; ++kt){
    int k0 = kt << 5;
    __syncthreads();
    // A: load f32, convert (pkrtz), write LDS (pitch 40)
    {
      const float4* ap = (const float4*)(abase + k0);
      float4 a0 = ap[0], a1 = ap[1], a2 = ap[2], a3 = ap[3];
      union { fp16x2 h2[8]; uint4 u[2]; } cv;
      cv.h2[0] = __builtin_amdgcn_cvt_pkrtz(a0.x, a0.y);
      cv.h2[1] = __builtin_amdgcn_cvt_pkrtz(a0.z, a0.w);
      cv.h2[2] = __builtin_amdgcn_cvt_pkrtz(a1.x, a1.y);
      cv.h2[3] = __builtin_amdgcn_cvt_pkrtz(a1.z, a1.w);
      cv.h2[4] = __builtin_amdgcn_cvt_pkrtz(a2.x, a2.y);
      cv.h2[5] = __builtin_amdgcn_cvt_pkrtz(a2.z, a2.w);
      cv.h2[6] = __builtin_amdgcn_cvt_pkrtz(a3.x, a3.y);
      cv.h2[7] = __builtin_amdgcn_cvt_pkrtz(a3.z, a3.w);
      *(uint4*)(As + arow * 40 + acol)     = cv.u[0];
      *(uint4*)(As + arow * 40 + acol + 8) = cv.u[1];
    }
    // B: async 16B global->LDS (pitch 32, contiguous)
    #pragma unroll
    for (int i = 0; i < 2; ++i){
      int c = (w << 7) + (i << 6) + lane;
      gl_lds16(Bt + (size_t)((bn << 7) + (c >> 2)) * K + k0 + ((c & 3) << 3),
               Bs + ((w << 7) + (i << 6)) * 8);
    }
    __syncthreads();
    f16x8 af[4], bfr[4];
    #pragma unroll
    for (int mi = 0; mi < 4; ++mi)
      af[mi] = *(const f16x8*)(As + (wm + mi * 16 + lrow) * 40 + quad * 8);
    #pragma unroll
    for (int ni = 0; ni < 4; ++ni)
      bfr[ni] = *(const f16x8*)(Bs + (wn + ni * 16 + lrow) * 32 + quad * 8);
    #pragma unroll
    for (int mi = 0; mi < 4; ++mi)
      #pragma unroll
      for (int ni = 0; ni < 4; ++ni)
        acc[mi][ni] = __builtin_amdgcn_mfma_f32_16x16x32_f16(af[mi], bfr[ni], acc[mi][ni], 0, 0, 0);
  }

  #pragma unroll
  for (int mi = 0; mi < 4; ++mi)
    #pragma unroll
    for (int ni = 0; ni < 4; ++ni)
      #pragma unroll
      for (int r = 0; r < 4; ++r){
        int row = (bm << 7) + wm + mi * 16 + quad * 4 + r;
        int col = (bn << 7) + wn + ni * 16 + lrow;
        Cout[(size_t)row * N + col] = (f16)acc[mi][ni][r];
      }
}

// ---------------- GEMM: C[M][N] = A[M][K] @ Bt[N][K]^T, f16 in, f32 out ----------------
__global__ __launch_bounds__(256) void gemm_f16_kernel(const f16* __restrict__ A,
                                                       const f16* __restrict__ Bt,
                                                       float* __restrict__ Cout,
                                                       int M, int N, int K){
  __shared__ __align__(16) f16 As[128 * 32];
  __shared__ __align__(16) f16 Bs[128 * 32];
  int t = threadIdx.x;
  int w = t >> 6, lane = t & 63;
  int wm = (w >> 1) * 64, wn = (w & 1) * 64;
  int lrow = lane & 15, quad = lane >> 4;
  int bm = blockIdx.y, bn = blockIdx.x;

  f32x4 acc[4][4];
  for (int i = 0; i < 4; ++i)
    for (int j = 0; j < 4; ++j)
      for (int r = 0; r < 4; ++r) acc[i][j][r] = 0.f;

  const int nk = K >> 5;
  for (int kt = 0; kt < nk; ++kt){
    int k0 = kt << 5;
    __syncthreads();
    #pragma unroll
    for (int i = 0; i < 2; ++i){
      int c = (w << 7) + (i << 6) + lane;
      gl_lds16(A  + (size_t)((bm << 7) + (c >> 2)) * K + k0 + ((c & 3) << 3),
               As + ((w << 7) + (i << 6)) * 8);
      gl_lds16(Bt + (size_t)((bn << 7) + (c >> 2)) * K + k0 + ((c & 3) << 3),
               Bs + ((w << 7) + (i << 6)) * 8);
    }
    __syncthreads();
    f16x8 af[4], bfr[4];
    #pragma unroll
    for (int mi = 0; mi < 4; ++mi)
      af[mi] = *(const f16x8*)(As + (wm + mi * 16 + lrow) * 32 + quad * 8);
    #pragma unroll
    for (int ni = 0; ni < 4; ++ni)
      bfr[ni] = *(const f16x8*)(Bs + (wn + ni * 16 + lrow) * 32 + quad * 8);
    #pragma unroll
    for (int mi = 0; mi < 4; ++mi)
      #pragma unroll
      for (int ni = 0; ni < 4; ++ni)
        acc[mi][ni] = __builtin_amdgcn_mfma_f32_16x16x32_f16(af[mi], bfr[ni], acc[mi][ni], 0, 0, 0);
  }

  #pragma unroll
  for (int mi = 0; mi < 4; ++mi)
    #pragma unroll
    for (int ni = 0; ni < 4; ++ni)
      #pragma unroll
      for (int r = 0; r < 4; ++r){
        int row = (bm << 7) + wm + mi * 16 + quad * 4 + r;
        int col = (bn << 7) + wn + ni * 16 + lrow;
        Cout[(size_t)row * N + col] = acc[mi][ni][r];
      }
}

// ---------------- fused causal graph attention, split-K chunks (CH tiles) ----------------
// grid (32 bh, 32 qt, MAXCH c0); invalid chunks exit. qt<CH: direct write; else partials.
__global__ __launch_bounds__(256, 4) void attn_kernel(const f16* __restrict__ qkv,
                                                      const float* __restrict__ gadj,
                                                      const int* __restrict__ etype,
                                                      const float* __restrict__ adj_bias,
                                                      const float* __restrict__ edge_table,
                                                      f16* __restrict__ attn_out,
                                                      f16* __restrict__ Opart,
                                                      float* __restrict__ MLpart,
                                                      int CH, int NQT, int MAXCH){
  __shared__ __align__(16) f16 Ks[64 * 72];
  __shared__ __align__(16) f16 Vt[64 * 72];   // transposed [hd][key], xor-swizzled 16B blocks
  __shared__ __align__(16) f16 Ps[4][16 * 72];
  __shared__ float edge_lds[8 * 33];

  int bh = blockIdx.x;
  int h = bh & 15;
  int b = bh >> 4;
  int qt = 31 - (int)blockIdx.y;
  int c0 = blockIdx.z;
  int ks = c0 * CH;
  if (ks > qt) return;
  int ke = min(qt, ks + CH - 1);
  bool whole = (qt < CH);

  int t = threadIdx.x;
  int w = t >> 6, lane = t & 63;
  int lrow = lane & 15, quad = lane >> 4;

  if (t < 136){
    int cp = t / 17, e = t - cp * 17;
    edge_lds[cp * 33 + e] = edge_table[e * HH + h];
  }
  float adjb = adj_bias[h];
  int erep = (lane & 7) * 33;

  int q0 = qt * 64 + w * 16;
  int qgb = q0 + quad * 4;
  const size_t qrow = ((size_t)b * TT + q0 + lrow) * 3072 + h * 64;
  f16x8 qf0 = *(const f16x8*)(qkv + qrow + quad * 8);
  f16x8 qf1 = *(const f16x8*)(qkv + qrow + 32 + quad * 8);
  #pragma unroll
  for (int i = 0; i < 8; ++i){ qf0[i] *= (f16)0.125f; qf1[i] *= (f16)0.125f; }

  f32x4 o[4];
  for (int i = 0; i < 4; ++i)
    for (int r = 0; r < 4; ++r) o[i][r] = 0.f;
  float mrun[4] = {-1e30f, -1e30f, -1e30f, -1e30f};
  float lrun[4] = {0.f, 0.f, 0.f, 0.f};

  const int keyA = t >> 3,        hdA = (t & 7) << 3;
  const int keyB = 32 + (t >> 3), hdB = hdA;
  const int sA = ((keyA >> 3) ^ (hdA >> 3)) & 7;
  const int sB = ((keyB >> 3) ^ (hdB >> 3)) & 7;
  const f16* kbase = qkv + (size_t)b * TT * 3072 + 1024 + h * 64;
  const f16* vbase = qkv + (size_t)b * TT * 3072 + 2048 + h * 64;

  float gv[16]; int ev[16];
  auto load_bias = [&](int kt){
    int kg0 = kt * 64 + lrow;
    #pragma unroll
    for (int nb = 0; nb < 4; ++nb){
      size_t idx0 = ((size_t)b * TT + qgb) * TT + kg0 + nb * 16;
      #pragma unroll
      for (int r = 0; r < 4; ++r){
        size_t idx = idx0 + (size_t)r * TT;
        gv[nb * 4 + r] = gadj[idx];
        ev[nb * 4 + r] = etype[idx];
      }
    }
  };
  load_bias(ks);   // prefetch first tile's bias

  for (int kt2 = ks; kt2 <= ke; ++kt2){
    lds_barrier();   // prev-iter LDS reads done; outstanding global loads stay in flight
    uint4 kv0 = *(const uint4*)(kbase + (size_t)(kt2 * 64 + keyA) * 3072 + hdA);
    uint4 kv1 = *(const uint4*)(kbase + (size_t)(kt2 * 64 + keyB) * 3072 + hdB);
    uint4 vv0 = *(const uint4*)(vbase + (size_t)(kt2 * 64 + keyA) * 3072 + hdA);
    uint4 vv1 = *(const uint4*)(vbase + (size_t)(kt2 * 64 + keyB) * 3072 + hdB);

    *(uint4*)(Ks + keyA * 72 + hdA) = kv0;
    *(uint4*)(Ks + keyB * 72 + hdB) = kv1;
    {
      union { uint4 u; f16 hh[8]; } ua, ub;
      ua.u = vv0; ub.u = vv1;
      #pragma unroll
      for (int jj = 0; jj < 8; ++jj){
        Vt[(hdA + jj) * 72 + (sA << 3) + (keyA & 7)] = ua.hh[jj];
        Vt[(hdB + jj) * 72 + (sB << 3) + (keyB & 7)] = ub.hh[jj];
      }
    }
    lds_barrier();

    // S = Q K^T (Q pre-scaled by 1/8)
    f32x4 sf[4];
    #pragma unroll
    for (int nb = 0; nb < 4; ++nb){
      f32x4 s = {0.f, 0.f, 0.f, 0.f};
      f16x8 kf0 = *(const f16x8*)(Ks + (nb * 16 + lrow) * 72 + quad * 8);
      f16x8 kf1 = *(const f16x8*)(Ks + (nb * 16 + lrow) * 72 + 32 + quad * 8);
      s = __builtin_amdgcn_mfma_f32_16x16x32_f16(qf0, kf0, s, 0, 0, 0);
      s = __builtin_amdgcn_mfma_f32_16x16x32_f16(qf1, kf1, s, 0, 0, 0);
      sf[nb] = s;
    }

    // bias + causal mask, consuming prefetched gv/ev
    float sarr[4][4];
    bool diag = (kt2 == qt);
    #pragma unroll
    for (int nb = 0; nb < 4; ++nb){
      int kg = kt2 * 64 + lrow + nb * 16;
      #pragma unroll
      for (int r = 0; r < 4; ++r){
        float v;
        if (diag && kg > qgb + r) v = -1e30f;
        else v = sf[nb][r] + fmaf(adjb, gv[nb * 4 + r], edge_lds[erep + ev[nb * 4 + r]]);
        sarr[nb][r] = v;
      }
    }

    // prefetch next tile's bias (in flight across next barrier: lds_barrier keeps vmcnt open)
    load_bias(kt2 < ke ? kt2 + 1 : ke);

    // online softmax (rows across 16 lanes of a quad)
    float pv_[4][4];
    #pragma unroll
    for (int r = 0; r < 4; ++r){
      float mx = fmaxf(fmaxf(sarr[0][r], sarr[1][r]), fmaxf(sarr[2][r], sarr[3][r]));
      mx = fmaxf(mx, __shfl_xor(mx, 1));
      mx = fmaxf(mx, __shfl_xor(mx, 2));
      mx = fmaxf(mx, __shfl_xor(mx, 4));
      mx = fmaxf(mx, __shfl_xor(mx, 8));
      float mnew = fmaxf(mrun[r], mx);
      float alpha = exp2f((mrun[r] - mnew) * LOG2E);
      mrun[r] = mnew;
      float rs = 0.f;
      #pragma unroll
      for (int nb = 0; nb < 4; ++nb){
        float p = exp2f((sarr[nb][r] - mnew) * LOG2E);
        pv_[nb][r] = p; rs += p;
      }
      rs += __shfl_xor(rs, 1); rs += __shfl_xor(rs, 2);
      rs += __shfl_xor(rs, 4); rs += __shfl_xor(rs, 8);
      lrun[r] = lrun[r] * alpha + rs;
      #pragma unroll
      for (int nbh = 0; nbh < 4; ++nbh) o[nbh][r] *= alpha;
    }

    // P: C-layout -> LDS (pitch 72) -> A-layout (wave-private)
    f16* Pw = &Ps[w][0];
    #pragma unroll
    for (int nb = 0; nb < 4; ++nb)
      #pragma unroll
      for (int r = 0; r < 4; ++r)
        Pw[(quad * 4 + r) * 72 + nb * 16 + lrow] = (f16)pv_[nb][r];
    __asm__ volatile("s_waitcnt lgkmcnt(0)" ::: "memory");

    // O += P V  (Vt b128 fragments, swizzled)
    #pragma unroll
    for (int cc = 0; cc < 2; ++cc){
      f16x8 pf = *(const f16x8*)(Pw + lrow * 72 + cc * 32 + quad * 8);
      #pragma unroll
      for (int nbh = 0; nbh < 4; ++nbh){
        int hd = nbh * 16 + lrow;
        int sb = (hd >> 3) & 7;
        f16x8 vf = *(const f16x8*)(Vt + hd * 72 + (((cc * 4 + quad) ^ sb) << 3));
        o[nbh] = __builtin_amdgcn_mfma_f32_16x16x32_f16(pf, vf, o[nbh], 0, 0, 0);
      }
    }
  }

  if (whole){
    float inv[4];
    #pragma unroll
    for (int r = 0; r < 4; ++r) inv[r] = 1.0f / lrun[r];
    #pragma unroll
    for (int nbh = 0; nbh < 4; ++nbh)
      #pragma unroll
      for (int r = 0; r < 4; ++r){
        int qg = q0 + quad * 4 + r;
        int col = h * 64 + nbh * 16 + lrow;
        attn_out[((size_t)b * TT + qg) * 1024 + col] = (f16)(o[nbh][r] * inv[r]);
      }
  } else {
    int slot = (bh * NQT + (qt - CH)) * MAXCH + c0;
    f16* Ob = Opart + (size_t)slot * 4096;
    #pragma unroll
    for (int nbh = 0; nbh < 4; ++nbh)
      #pragma unroll
      for (int r = 0; r < 4; ++r)
        Ob[(w * 16 + quad * 4 + r) * 64 + nbh * 16 + lrow] = (f16)o[nbh][r];
    if (lrow == 0){
      #pragma unroll
      for (int r = 0; r < 4; ++r){
        int qq = w * 16 + quad * 4 + r;
        MLpart[(size_t)slot * 128 + qq] = mrun[r];
        MLpart[(size_t)slot * 128 + 64 + qq] = lrun[r];
      }
    }
  }
}

// ---------------- combine partials (2..4 chunks) ----------------
__global__ __launch_bounds__(256) void combine_kernel(const f16* __restrict__ Opart,
                                                      const float* __restrict__ ML,
                                                      f16* __restrict__ attn_out,
                                                      int CH, int NQT, int MAXCH){
  int bh = blockIdx.x, qy = blockIdx.y;
  int qt = CH + qy;
  int h = bh & 15, b = bh >> 4;
  int nch = (qt + CH) / CH;   // ceil((qt+1)/CH), 2..MAXCH
  int t = threadIdx.x;
  int q = t >> 2;
  int hd0 = (t & 3) << 4;
  int slot0 = (bh * NQT + qy) * MAXCH;

  float m[4], l[4], wgt[4];
  float M = -1e30f;
  for (int c = 0; c < nch; ++c){
    m[c] = ML[(size_t)(slot0 + c) * 128 + q];
    l[c] = ML[(size_t)(slot0 + c) * 128 + 64 + q];
    M = fmaxf(M, m[c]);
  }
  float L = 0.f;
  for (int c = 0; c < nch; ++c){ wgt[c] = exp2f((m[c] - M) * LOG2E); L += l[c] * wgt[c]; }
  float invL = 1.0f / L;

  float acc[16];
  #pragma unroll
  for (int i = 0; i < 16; ++i) acc[i] = 0.f;
  for (int c = 0; c < nch; ++c){
    const f16* O = Opart + (size_t)(slot0 + c) * 4096 + q * 64 + hd0;
    f16x8 a0 = *(const f16x8*)O, a1 = *(const f16x8*)(O + 8);
    #pragma unroll
    for (int i = 0; i < 8; ++i){
      acc[i]     += wgt[c] * (float)a0[i];
      acc[i + 8] += wgt[c] * (float)a1[i];
    }
  }
  f16 outv[16];
  #pragma unroll
  for (int i = 0; i < 16; ++i) outv[i] = (f16)(acc[i] * invL);
  int qg = qt * 64 + q;
  f16* dst = attn_out + ((size_t)b * TT + qg) * 1024 + h * 64 + hd0;
  *(uint4*)dst = *(uint4*)&outv[0];
  *(uint4*)(dst + 8) = *(uint4*)&outv[8];
}

extern "C" void kernel_launch(void* const* d_in, const int* in_sizes, int n_in,
                              void* d_out, int out_size, void* d_ws, size_t ws_size,
                              hipStream_t stream){
  (void)in_sizes; (void)n_in; (void)out_size;
  const float* x_f32  = (const float*)d_in[0];
  const float* gadj   = (const float*)d_in[1];
  const int*   etype  = (const int*)d_in[2];
  const float* wqkv   = (const float*)d_in[3];
  const float* wproj  = (const float*)d_in[4];
  const float* adjb   = (const float*)d_in[5];
  const float* etab   = (const float*)d_in[6];

  // Split config: CH=8 (finer, more blocks) if ws allows, else CH=16 (proven 42.5 MB).
  const int CH    = (ws_size >= 62390272ull) ? 8 : 16;
  const int NQT   = 32 - CH;           // #qt values with partials
  const int MAXCH = (CH == 8) ? 4 : 2;

  char* ws = (char*)d_ws;
  f16*   qkv    = (f16*)(ws);                           // [0, 25165824)
  f16*   attn_o = (f16*)(ws + 25165824);                // [.., 33554432)
  f16*   wprojT = (f16*)(ws + 33554432);                // [.., 35651584)
  f16*   wqkvT  = (f16*)(ws + 35651584);                // [.., 41943040), dead after gemm_xa
  f16*   Opart  = (f16*)(ws + 35651584);                // overlays wqkvT after gemm_xa
  size_t opart_bytes = (size_t)32 * NQT * MAXCH * 4096 * 2;
  float* MLpart = (float*)(ws + 35651584 + opart_bytes);

  transpose_cvt_kernel<<<dim3(48, 16), 256, 0, stream>>>(wqkv, wqkvT, 1024, 3072);
  transpose_cvt_kernel<<<dim3(16, 16), 256, 0, stream>>>(wproj, wprojT, 1024, 1024);
  gemm_xa_kernel<<<dim3(24, 32), 256, 0, stream>>>(x_f32, wqkvT, qkv, 4096, 3072, 1024);
  attn_kernel<<<dim3(32, 32, MAXCH), 256, 0, stream>>>(qkv, gadj, etype, adjb, etab,
                                                       attn_o, Opart, MLpart, CH, NQT, MAXCH);
  combine_kernel<<<dim3(32, NQT), 256, 0, stream>>>(Opart, MLpart, attn_o, CH, NQT, MAXCH);
  gemm_f16_kernel<<<dim3(8, 32), 256, 0, stream>>>(attn_o, wprojT, (float*)d_out, 4096, 1024, 1024);
}